// Round 6
// baseline (617.401 us; speedup 1.0000x reference)
//
#include <hip/hip_runtime.h>
#include <hip/hip_bf16.h>

#define NUM_EXPERTS 8
#define HIDDEN 2048
#define INTER 1024
#define T_TOKENS 4096

#define BK 32
#define GU_BM 64
#define GU_BN 128
#define DN_BM 64
#define DN_BN 128

typedef __attribute__((ext_vector_type(8))) short short8;
typedef __attribute__((ext_vector_type(4))) float f32x4;

__device__ __forceinline__ ushort f2bf(float f) {
    __hip_bfloat16 h = __float2bfloat16(f);
    return *reinterpret_cast<ushort*>(&h);
}

__device__ __forceinline__ void load_lds16(const void* g, void* lds) {
    __builtin_amdgcn_global_load_lds(
        (const __attribute__((address_space(1))) void*)g,
        (__attribute__((address_space(3))) void*)lds, 16, 0, 0);
}

// ---------------- fp32 -> bf16 conversion ----------------
__global__ __launch_bounds__(256) void cvt_bf16(const float* __restrict__ in,
                                                ushort* __restrict__ out, int n4) {
    int i = blockIdx.x * 256 + threadIdx.x;
    int stride = gridDim.x * 256;
    for (; i < n4; i += stride) {
        float4 v = reinterpret_cast<const float4*>(in)[i];
        ushort4 o;
        o.x = f2bf(v.x); o.y = f2bf(v.y); o.z = f2bf(v.z); o.w = f2bf(v.w);
        reinterpret_cast<ushort4*>(out)[i] = o;
    }
}

// ---------------- router: 4 waves/block, 1 token/wave ----------------
__global__ __launch_bounds__(256) void moe_router(const float* __restrict__ x,
                                                  const float* __restrict__ gw,
                                                  int* __restrict__ top_idx,
                                                  float* __restrict__ top_w,
                                                  int* __restrict__ counts) {
    int wid = threadIdx.x >> 6;
    int lane = threadIdx.x & 63;
    int t = blockIdx.x * 4 + wid;
    if (t >= T_TOKENS) return;
    const float* xt = x + (size_t)t * HIDDEN;
    float acc[NUM_EXPERTS];
#pragma unroll
    for (int e = 0; e < NUM_EXPERTS; e++) acc[e] = 0.f;
    for (int h = lane; h < HIDDEN; h += 64) {
        float xv = xt[h];
#pragma unroll
        for (int e = 0; e < NUM_EXPERTS; e++)
            acc[e] = fmaf(xv, gw[e * HIDDEN + h], acc[e]);
    }
#pragma unroll
    for (int e = 0; e < NUM_EXPERTS; e++) {
#pragma unroll
        for (int off = 32; off > 0; off >>= 1)
            acc[e] += __shfl_xor(acc[e], off);
    }
    if (lane == 0) {
        int i1 = 0; float l1 = acc[0];
#pragma unroll
        for (int e = 1; e < NUM_EXPERTS; e++)
            if (acc[e] > l1) { l1 = acc[e]; i1 = e; }
        int i2 = -1; float l2 = -3.4e38f;
#pragma unroll
        for (int e = 0; e < NUM_EXPERTS; e++)
            if (e != i1 && acc[e] > l2) { l2 = acc[e]; i2 = e; }
        float w2 = __expf(l2 - l1);
        float denom = 1.f + w2;
        top_idx[t * 2 + 0] = i1;
        top_idx[t * 2 + 1] = i2;
        top_w[t * 2 + 0] = 1.f / denom;
        top_w[t * 2 + 1] = w2 / denom;
        atomicAdd(&counts[i1], 1);
        atomicAdd(&counts[i2], 1);
    }
}

// ---------------- offsets ----------------
__global__ void moe_offsets(const int* __restrict__ counts,
                            int* __restrict__ ebase, int* __restrict__ cursor) {
    if (threadIdx.x == 0 && blockIdx.x == 0) {
        int s = 0;
        for (int e = 0; e < NUM_EXPERTS; e++) {
            ebase[e] = s; cursor[e] = s; s += counts[e];
        }
    }
}

// ---------------- scatter ----------------
__global__ __launch_bounds__(256) void moe_scatter(const int* __restrict__ top_idx,
                                                   const float* __restrict__ top_w,
                                                   int* __restrict__ cursor,
                                                   int* __restrict__ slot_tok,
                                                   float* __restrict__ slot_w) {
    int t = blockIdx.x * 256 + threadIdx.x;
    if (t >= T_TOKENS) return;
#pragma unroll
    for (int k = 0; k < 2; k++) {
        int e = top_idx[t * 2 + k];
        int pos = atomicAdd(&cursor[e], 1);
        slot_tok[pos] = t;
        slot_w[pos] = top_w[t * 2 + k];
    }
}

// ---------------- fused gate/up GEMM + SwiGLU ----------------
// 64x128 tile, 2-deep counted-vmcnt pipeline (T4), XOR bank-swizzle via
// pre-swizzled global source, XCD-chunked 1D grid (expert e -> XCD e).
__global__ __launch_bounds__(256, 4) void moe_gateup(const ushort* __restrict__ xb,
                                                     const ushort* __restrict__ wgb,
                                                     const ushort* __restrict__ wub,
                                                     const int* __restrict__ slot_tok,
                                                     const int* __restrict__ ebase,
                                                     const int* __restrict__ ecnt,
                                                     ushort* __restrict__ act) {
    __shared__ ushort ldsA[2][GU_BM * BK];   // 2 x 4 KB
    __shared__ ushort ldsG[2][GU_BN * BK];   // 2 x 8 KB
    __shared__ ushort ldsU[2][GU_BN * BK];   // 2 x 8 KB

    // grid = 4096 1D. XCD swizzle: xcd = wg&7 gets chunk of 512 = one expert.
    // Within expert: bm-major (consecutive ids share the bn weight panel).
    const int wg = blockIdx.x;
    const int wgid = (wg & 7) * 512 + (wg >> 3);
    const int e = wgid >> 9;
    const int rem = wgid & 511;
    const int bm = rem & 63;
    const int bn = rem >> 6;

    const int cnt = ecnt[e];
    if (bm * GU_BM >= cnt) return;
    const int b0 = ebase[e];

    const int tid = threadIdx.x;
    const int lane = tid & 63;
    const int wid = tid >> 6;
    const int wr = wid >> 1, wc = wid & 1;   // wave 2x2: 32 rows x 64 cols

    // ---- staging sources (col pre-swizzled; LDS written linearly) ----
    const int r = tid >> 2, cs = tid & 3;
    const int scl = (cs ^ ((r >> 1) & 3)) * 8;
    const int ar = bm * GU_BM + r;
    const int tok = slot_tok[b0 + ((ar < cnt) ? ar : (cnt - 1))];
    const ushort* pA = xb + (size_t)tok * HIDDEN + scl;
    const size_t wrow0 = (size_t)e * INTER + (size_t)(bn * GU_BN + r);
    const ushort* pG0 = wgb + wrow0 * HIDDEN + scl;
    const ushort* pG1 = pG0 + (size_t)64 * HIDDEN;
    const ushort* pU0 = wub + wrow0 * HIDDEN + scl;
    const ushort* pU1 = pU0 + (size_t)64 * HIDDEN;

    const int fr = lane & 15;
    const int colsw = (((lane >> 4) ^ ((fr >> 1) & 3)) * 8);

    f32x4 accg[2][4] = {};
    f32x4 accu[2][4] = {};

#define GU_STAGE(buf, t)                                              \
    do {                                                              \
        const int _o = (t) * BK;                                      \
        load_lds16(pA + _o,  &ldsA[buf][tid * 8]);                    \
        load_lds16(pG0 + _o, &ldsG[buf][tid * 8]);                    \
        load_lds16(pG1 + _o, &ldsG[buf][2048 + tid * 8]);             \
        load_lds16(pU0 + _o, &ldsU[buf][tid * 8]);                    \
        load_lds16(pU1 + _o, &ldsU[buf][2048 + tid * 8]);             \
    } while (0)

#define GU_FRAGS_MFMA(cur)                                            \
    do {                                                              \
        const ushort* LA = ldsA[cur];                                 \
        const ushort* LG = ldsG[cur];                                 \
        const ushort* LU = ldsU[cur];                                 \
        short8 a[2], bg[4], bu[4];                                    \
        _Pragma("unroll")                                             \
        for (int m = 0; m < 2; m++)                                   \
            a[m] = *(const short8*)(LA + (wr * 32 + m * 16 + fr) * BK + colsw); \
        _Pragma("unroll")                                             \
        for (int n = 0; n < 4; n++) {                                 \
            bg[n] = *(const short8*)(LG + (wc * 64 + n * 16 + fr) * BK + colsw); \
            bu[n] = *(const short8*)(LU + (wc * 64 + n * 16 + fr) * BK + colsw); \
        }                                                             \
        asm volatile("s_waitcnt lgkmcnt(0)" ::: "memory");            \
        asm volatile("s_barrier" ::: "memory");                       \
        if (t + 2 < NT) GU_STAGE(cur, t + 2);                         \
        _Pragma("unroll")                                             \
        for (int m = 0; m < 2; m++) {                                 \
            _Pragma("unroll")                                         \
            for (int n = 0; n < 4; n++) {                             \
                accg[m][n] = __builtin_amdgcn_mfma_f32_16x16x32_bf16(a[m], bg[n], accg[m][n], 0, 0, 0); \
                accu[m][n] = __builtin_amdgcn_mfma_f32_16x16x32_bf16(a[m], bu[n], accu[m][n], 0, 0, 0); \
            }                                                         \
        }                                                             \
    } while (0)

    const int NT = HIDDEN / BK;   // 64
    GU_STAGE(0, 0);
    GU_STAGE(1, 1);

    for (int t = 0; t < NT - 1; ++t) {
        // wait for stage t (oldest 5 of <=10 outstanding); stage t+1 stays in flight
        asm volatile("s_waitcnt vmcnt(5)" ::: "memory");
        asm volatile("s_barrier" ::: "memory");
        const int cur = t & 1;
        GU_FRAGS_MFMA(cur);
    }
    {
        const int t = NT - 1;
        asm volatile("s_waitcnt vmcnt(0)" ::: "memory");
        asm volatile("s_barrier" ::: "memory");
        const int cur = t & 1;
        GU_FRAGS_MFMA(cur);
    }
#undef GU_FRAGS_MFMA
#undef GU_STAGE

    // epilogue: SwiGLU, cast bf16, store act[slot][col]
#pragma unroll
    for (int m = 0; m < 2; m++) {
#pragma unroll
        for (int rr = 0; rr < 4; rr++) {
            int row = bm * GU_BM + wr * 32 + m * 16 + (lane >> 4) * 4 + rr;
            if (row < cnt) {
                size_t arow = (size_t)(b0 + row) * INTER;
#pragma unroll
                for (int n = 0; n < 4; n++) {
                    int col = bn * GU_BN + wc * 64 + n * 16 + fr;
                    float g = accg[m][n][rr];
                    float u = accu[m][n][rr];
                    float s = g / (1.f + __expf(-g));
                    act[arow + col] = f2bf(s * u);
                }
            }
        }
    }
}

// ---------------- down GEMM + routed atomic accumulate ----------------
__global__ __launch_bounds__(256, 6) void moe_down(const ushort* __restrict__ act,
                                                   const ushort* __restrict__ wdb,
                                                   const int* __restrict__ slot_tok,
                                                   const float* __restrict__ slot_w,
                                                   const int* __restrict__ ebase,
                                                   const int* __restrict__ ecnt,
                                                   float* __restrict__ out) {
    __shared__ ushort ldsA[2][DN_BM * BK];   // 2 x 4 KB
    __shared__ ushort ldsB[2][DN_BN * BK];   // 2 x 8 KB

    // grid = 8192 1D; xcd = wg&7 gets 1024 = one expert, bm-major.
    const int wg = blockIdx.x;
    const int wgid = (wg & 7) * 1024 + (wg >> 3);
    const int e = wgid >> 10;
    const int rem = wgid & 1023;
    const int bm = rem & 63;
    const int bn = rem >> 6;

    const int cnt = ecnt[e];
    if (bm * DN_BM >= cnt) return;
    const int b0 = ebase[e];

    const int tid = threadIdx.x;
    const int lane = tid & 63;
    const int wid = tid >> 6;
    const int wr = wid >> 1, wc = wid & 1;

    const int r = tid >> 2, cs = tid & 3;
    const int scl = (cs ^ ((r >> 1) & 3)) * 8;
    const int ar = bm * DN_BM + r;
    const int sr = b0 + ((ar < cnt) ? ar : (cnt - 1));
    const ushort* pA = act + (size_t)sr * INTER + scl;
    const size_t wrow = (size_t)e * HIDDEN + (size_t)(bn * DN_BN + r);
    const ushort* pB0 = wdb + wrow * INTER + scl;
    const ushort* pB1 = pB0 + (size_t)64 * INTER;

    const int fr = lane & 15;
    const int colsw = (((lane >> 4) ^ ((fr >> 1) & 3)) * 8);

    f32x4 acc[2][4] = {};

#define DN_STAGE(buf, t)                                              \
    do {                                                              \
        const int _o = (t) * BK;                                      \
        load_lds16(pA + _o,  &ldsA[buf][tid * 8]);                    \
        load_lds16(pB0 + _o, &ldsB[buf][tid * 8]);                    \
        load_lds16(pB1 + _o, &ldsB[buf][2048 + tid * 8]);             \
    } while (0)

#define DN_FRAGS_MFMA(cur)                                            \
    do {                                                              \
        const ushort* LA = ldsA[cur];                                 \
        const ushort* LB = ldsB[cur];                                 \
        short8 a[2], b[4];                                            \
        _Pragma("unroll")                                             \
        for (int m = 0; m < 2; m++)                                   \
            a[m] = *(const short8*)(LA + (wr * 32 + m * 16 + fr) * BK + colsw); \
        _Pragma("unroll")                                             \
        for (int n = 0; n < 4; n++)                                   \
            b[n] = *(const short8*)(LB + (wc * 64 + n * 16 + fr) * BK + colsw); \
        asm volatile("s_waitcnt lgkmcnt(0)" ::: "memory");            \
        asm volatile("s_barrier" ::: "memory");                       \
        if (t + 2 < NT) DN_STAGE(cur, t + 2);                         \
        _Pragma("unroll")                                             \
        for (int m = 0; m < 2; m++) {                                 \
            _Pragma("unroll")                                         \
            for (int n = 0; n < 4; n++)                               \
                acc[m][n] = __builtin_amdgcn_mfma_f32_16x16x32_bf16(a[m], b[n], acc[m][n], 0, 0, 0); \
        }                                                             \
    } while (0)

    const int NT = INTER / BK;   // 32
    DN_STAGE(0, 0);
    DN_STAGE(1, 1);

    for (int t = 0; t < NT - 1; ++t) {
        asm volatile("s_waitcnt vmcnt(3)" ::: "memory");
        asm volatile("s_barrier" ::: "memory");
        const int cur = t & 1;
        DN_FRAGS_MFMA(cur);
    }
    {
        const int t = NT - 1;
        asm volatile("s_waitcnt vmcnt(0)" ::: "memory");
        asm volatile("s_barrier" ::: "memory");
        const int cur = t & 1;
        DN_FRAGS_MFMA(cur);
    }
#undef DN_FRAGS_MFMA
#undef DN_STAGE

#pragma unroll
    for (int m = 0; m < 2; m++) {
#pragma unroll
        for (int rr = 0; rr < 4; rr++) {
            int row = bm * DN_BM + wr * 32 + m * 16 + (lane >> 4) * 4 + rr;
            if (row < cnt) {
                int slot = b0 + row;
                int tok = slot_tok[slot];
                float w = slot_w[slot];
                float* orow = out + (size_t)tok * HIDDEN;
#pragma unroll
                for (int n = 0; n < 4; n++) {
                    int col = bn * DN_BN + wc * 64 + n * 16 + fr;
                    atomicAdd(&orow[col], acc[m][n][rr] * w);
                }
            }
        }
    }
}

// ---------------- launch ----------------
extern "C" void kernel_launch(void* const* d_in, const int* in_sizes, int n_in,
                              void* d_out, int out_size, void* d_ws, size_t ws_size,
                              hipStream_t stream) {
    const float* x  = (const float*)d_in[0];
    const float* gw = (const float*)d_in[1];
    const float* wg = (const float*)d_in[2];
    const float* wu = (const float*)d_in[3];
    const float* wd = (const float*)d_in[4];
    float* out = (float*)d_out;

    char* ws = (char*)d_ws;
    ushort* xb  = (ushort*)(ws);                                   // 16 MB
    ushort* wgb = (ushort*)(ws + 16777216);                        // 32 MB
    ushort* wub = (ushort*)(ws + 16777216 + 33554432);             // 32 MB
    ushort* wdb = (ushort*)(ws + 16777216 + 2u * 33554432);        // 32 MB
    ushort* act = (ushort*)(ws + 16777216 + 3u * 33554432);        // 16 MB
    char* p = ws + 2u * 16777216 + 3u * 33554432;
    int*   top_idx  = (int*)p;   p += 32768;
    float* top_w    = (float*)p; p += 32768;
    int*   slot_tok = (int*)p;   p += 32768;
    float* slot_w   = (float*)p; p += 32768;
    int*   counts   = (int*)p;   p += 128;
    int*   ebase    = (int*)p;   p += 128;
    int*   cursor   = (int*)p;   p += 128;

    hipMemsetAsync(counts, 0, 128, stream);
    hipMemsetAsync(d_out, 0, (size_t)out_size * sizeof(float), stream);

    cvt_bf16<<<1024, 256, 0, stream>>>(x,  xb,  (T_TOKENS * HIDDEN) / 4);
    cvt_bf16<<<1024, 256, 0, stream>>>(wg, wgb, (NUM_EXPERTS * INTER * HIDDEN) / 4);
    cvt_bf16<<<1024, 256, 0, stream>>>(wu, wub, (NUM_EXPERTS * INTER * HIDDEN) / 4);
    cvt_bf16<<<1024, 256, 0, stream>>>(wd, wdb, (NUM_EXPERTS * HIDDEN * INTER) / 4);

    moe_router<<<T_TOKENS / 4, 256, 0, stream>>>(x, gw, top_idx, top_w, counts);
    moe_offsets<<<1, 64, 0, stream>>>(counts, ebase, cursor);
    moe_scatter<<<(T_TOKENS + 255) / 256, 256, 0, stream>>>(top_idx, top_w, cursor, slot_tok, slot_w);

    moe_gateup<<<4096, 256, 0, stream>>>(xb, wgb, wub, slot_tok, ebase, counts, act);
    moe_down<<<8192, 256, 0, stream>>>(act, wdb, slot_tok, slot_w, ebase, counts, out);
}

// Round 7
// 600.740 us; speedup vs baseline: 1.0277x; 1.0277x over previous
//
#include <hip/hip_runtime.h>
#include <hip/hip_bf16.h>

#define NUM_EXPERTS 8
#define HIDDEN 2048
#define INTER 1024
#define T_TOKENS 4096

#define BK 32
#define GU_BM 64
#define GU_BN 128
#define DN_BM 64
#define DN_BN 128

typedef __attribute__((ext_vector_type(8))) short short8;
typedef __attribute__((ext_vector_type(8))) unsigned short ushort8_t;
typedef __attribute__((ext_vector_type(4))) float f32x4;

__device__ __forceinline__ ushort f2bf(float f) {
    __hip_bfloat16 h = __float2bfloat16(f);
    return *reinterpret_cast<ushort*>(&h);
}

__device__ __forceinline__ void load_lds16(const void* g, void* lds) {
    __builtin_amdgcn_global_load_lds(
        (const __attribute__((address_space(1))) void*)g,
        (__attribute__((address_space(3))) void*)lds, 16, 0, 0);
}

// ---------------- fp32 -> bf16 conversion (32B in / 16B out per iter) ----------------
__global__ __launch_bounds__(256) void cvt_bf16(const float* __restrict__ in,
                                                ushort* __restrict__ out, int n8) {
    int i = blockIdx.x * 256 + threadIdx.x;
    int stride = gridDim.x * 256;
    for (; i < n8; i += stride) {
        const float4* p = (const float4*)in + 2 * (size_t)i;
        float4 a = p[0], b = p[1];
        ushort8_t o;
        o[0] = f2bf(a.x); o[1] = f2bf(a.y); o[2] = f2bf(a.z); o[3] = f2bf(a.w);
        o[4] = f2bf(b.x); o[5] = f2bf(b.y); o[6] = f2bf(b.z); o[7] = f2bf(b.w);
        *((ushort8_t*)out + i) = o;
    }
}

// ---------------- router: 4 waves/block, 1 token/wave ----------------
__global__ __launch_bounds__(256) void moe_router(const float* __restrict__ x,
                                                  const float* __restrict__ gw,
                                                  int* __restrict__ top_idx,
                                                  float* __restrict__ top_w,
                                                  int* __restrict__ counts) {
    int wid = threadIdx.x >> 6;
    int lane = threadIdx.x & 63;
    int t = blockIdx.x * 4 + wid;
    if (t >= T_TOKENS) return;
    const float* xt = x + (size_t)t * HIDDEN;
    float acc[NUM_EXPERTS];
#pragma unroll
    for (int e = 0; e < NUM_EXPERTS; e++) acc[e] = 0.f;
    for (int h = lane; h < HIDDEN; h += 64) {
        float xv = xt[h];
#pragma unroll
        for (int e = 0; e < NUM_EXPERTS; e++)
            acc[e] = fmaf(xv, gw[e * HIDDEN + h], acc[e]);
    }
#pragma unroll
    for (int e = 0; e < NUM_EXPERTS; e++) {
#pragma unroll
        for (int off = 32; off > 0; off >>= 1)
            acc[e] += __shfl_xor(acc[e], off);
    }
    if (lane == 0) {
        int i1 = 0; float l1 = acc[0];
#pragma unroll
        for (int e = 1; e < NUM_EXPERTS; e++)
            if (acc[e] > l1) { l1 = acc[e]; i1 = e; }
        int i2 = -1; float l2 = -3.4e38f;
#pragma unroll
        for (int e = 0; e < NUM_EXPERTS; e++)
            if (e != i1 && acc[e] > l2) { l2 = acc[e]; i2 = e; }
        float w2 = __expf(l2 - l1);
        float denom = 1.f + w2;
        top_idx[t * 2 + 0] = i1;
        top_idx[t * 2 + 1] = i2;
        top_w[t * 2 + 0] = 1.f / denom;
        top_w[t * 2 + 1] = w2 / denom;
        atomicAdd(&counts[i1], 1);
        atomicAdd(&counts[i2], 1);
    }
}

// ---------------- offsets ----------------
__global__ void moe_offsets(const int* __restrict__ counts,
                            int* __restrict__ ebase, int* __restrict__ cursor) {
    if (threadIdx.x == 0 && blockIdx.x == 0) {
        int s = 0;
        for (int e = 0; e < NUM_EXPERTS; e++) {
            ebase[e] = s; cursor[e] = s; s += counts[e];
        }
    }
}

// ---------------- scatter (records inverse slot map for gather) ----------------
__global__ __launch_bounds__(256) void moe_scatter(const int* __restrict__ top_idx,
                                                   int* __restrict__ cursor,
                                                   int* __restrict__ slot_tok,
                                                   int* __restrict__ inv_slot) {
    int t = blockIdx.x * 256 + threadIdx.x;
    if (t >= T_TOKENS) return;
#pragma unroll
    for (int k = 0; k < 2; k++) {
        int e = top_idx[t * 2 + k];
        int pos = atomicAdd(&cursor[e], 1);
        slot_tok[pos] = t;
        inv_slot[t * 2 + k] = pos;
    }
}

// ---------------- fused gate/up GEMM + SwiGLU ----------------
__global__ __launch_bounds__(256, 4) void moe_gateup(const ushort* __restrict__ xb,
                                                     const ushort* __restrict__ wgb,
                                                     const ushort* __restrict__ wub,
                                                     const int* __restrict__ slot_tok,
                                                     const int* __restrict__ ebase,
                                                     const int* __restrict__ ecnt,
                                                     ushort* __restrict__ act) {
    __shared__ ushort ldsA[2][GU_BM * BK];   // 2 x 4 KB
    __shared__ ushort ldsG[2][GU_BN * BK];   // 2 x 8 KB
    __shared__ ushort ldsU[2][GU_BN * BK];   // 2 x 8 KB

    const int wg = blockIdx.x;
    const int wgid = (wg & 7) * 512 + (wg >> 3);
    const int e = wgid >> 9;
    const int rem = wgid & 511;
    const int bm = rem & 63;
    const int bn = rem >> 6;

    const int cnt = ecnt[e];
    if (bm * GU_BM >= cnt) return;
    const int b0 = ebase[e];

    const int tid = threadIdx.x;
    const int lane = tid & 63;
    const int wid = tid >> 6;
    const int wr = wid >> 1, wc = wid & 1;

    const int r = tid >> 2, cs = tid & 3;
    const int scl = (cs ^ ((r >> 1) & 3)) * 8;
    const int ar = bm * GU_BM + r;
    const int tok = slot_tok[b0 + ((ar < cnt) ? ar : (cnt - 1))];
    const ushort* pA = xb + (size_t)tok * HIDDEN + scl;
    const size_t wrow0 = (size_t)e * INTER + (size_t)(bn * GU_BN + r);
    const ushort* pG0 = wgb + wrow0 * HIDDEN + scl;
    const ushort* pG1 = pG0 + (size_t)64 * HIDDEN;
    const ushort* pU0 = wub + wrow0 * HIDDEN + scl;
    const ushort* pU1 = pU0 + (size_t)64 * HIDDEN;

    const int fr = lane & 15;
    const int colsw = (((lane >> 4) ^ ((fr >> 1) & 3)) * 8);

    f32x4 accg[2][4] = {};
    f32x4 accu[2][4] = {};

#define GU_STAGE(buf, t)                                              \
    do {                                                              \
        const int _o = (t) * BK;                                      \
        load_lds16(pA + _o,  &ldsA[buf][tid * 8]);                    \
        load_lds16(pG0 + _o, &ldsG[buf][tid * 8]);                    \
        load_lds16(pG1 + _o, &ldsG[buf][2048 + tid * 8]);             \
        load_lds16(pU0 + _o, &ldsU[buf][tid * 8]);                    \
        load_lds16(pU1 + _o, &ldsU[buf][2048 + tid * 8]);             \
    } while (0)

#define GU_FRAGS_MFMA(cur)                                            \
    do {                                                              \
        const ushort* LA = ldsA[cur];                                 \
        const ushort* LG = ldsG[cur];                                 \
        const ushort* LU = ldsU[cur];                                 \
        short8 a[2], bg[4], bu[4];                                    \
        _Pragma("unroll")                                             \
        for (int m = 0; m < 2; m++)                                   \
            a[m] = *(const short8*)(LA + (wr * 32 + m * 16 + fr) * BK + colsw); \
        _Pragma("unroll")                                             \
        for (int n = 0; n < 4; n++) {                                 \
            bg[n] = *(const short8*)(LG + (wc * 64 + n * 16 + fr) * BK + colsw); \
            bu[n] = *(const short8*)(LU + (wc * 64 + n * 16 + fr) * BK + colsw); \
        }                                                             \
        asm volatile("s_waitcnt lgkmcnt(0)" ::: "memory");            \
        asm volatile("s_barrier" ::: "memory");                       \
        if (t + 2 < NT) GU_STAGE(cur, t + 2);                         \
        _Pragma("unroll")                                             \
        for (int m = 0; m < 2; m++) {                                 \
            _Pragma("unroll")                                         \
            for (int n = 0; n < 4; n++) {                             \
                accg[m][n] = __builtin_amdgcn_mfma_f32_16x16x32_bf16(a[m], bg[n], accg[m][n], 0, 0, 0); \
                accu[m][n] = __builtin_amdgcn_mfma_f32_16x16x32_bf16(a[m], bu[n], accu[m][n], 0, 0, 0); \
            }                                                         \
        }                                                             \
    } while (0)

    const int NT = HIDDEN / BK;   // 64
    GU_STAGE(0, 0);
    GU_STAGE(1, 1);

    for (int t = 0; t < NT - 1; ++t) {
        asm volatile("s_waitcnt vmcnt(5)" ::: "memory");
        asm volatile("s_barrier" ::: "memory");
        const int cur = t & 1;
        GU_FRAGS_MFMA(cur);
    }
    {
        const int t = NT - 1;
        asm volatile("s_waitcnt vmcnt(0)" ::: "memory");
        asm volatile("s_barrier" ::: "memory");
        const int cur = t & 1;
        GU_FRAGS_MFMA(cur);
    }
#undef GU_FRAGS_MFMA
#undef GU_STAGE

#pragma unroll
    for (int m = 0; m < 2; m++) {
#pragma unroll
        for (int rr = 0; rr < 4; rr++) {
            int row = bm * GU_BM + wr * 32 + m * 16 + (lane >> 4) * 4 + rr;
            if (row < cnt) {
                size_t arow = (size_t)(b0 + row) * INTER;
#pragma unroll
                for (int n = 0; n < 4; n++) {
                    int col = bn * GU_BN + wc * 64 + n * 16 + fr;
                    float g = accg[m][n][rr];
                    float u = accu[m][n][rr];
                    float s = g / (1.f + __expf(-g));
                    act[arow + col] = f2bf(s * u);
                }
            }
        }
    }
}

// ---------------- down GEMM: plain fp32 stores to out_e[slot][H] ----------------
__global__ __launch_bounds__(256, 6) void moe_down(const ushort* __restrict__ act,
                                                   const ushort* __restrict__ wdb,
                                                   const int* __restrict__ ebase,
                                                   const int* __restrict__ ecnt,
                                                   float* __restrict__ out_e) {
    __shared__ ushort ldsA[2][DN_BM * BK];   // 2 x 4 KB
    __shared__ ushort ldsB[2][DN_BN * BK];   // 2 x 8 KB

    const int wg = blockIdx.x;
    const int wgid = (wg & 7) * 1024 + (wg >> 3);
    const int e = wgid >> 10;
    const int rem = wgid & 1023;
    const int bm = rem & 63;
    const int bn = rem >> 6;

    const int cnt = ecnt[e];
    if (bm * DN_BM >= cnt) return;
    const int b0 = ebase[e];

    const int tid = threadIdx.x;
    const int lane = tid & 63;
    const int wid = tid >> 6;
    const int wr = wid >> 1, wc = wid & 1;

    const int r = tid >> 2, cs = tid & 3;
    const int scl = (cs ^ ((r >> 1) & 3)) * 8;
    const int ar = bm * DN_BM + r;
    const int sr = b0 + ((ar < cnt) ? ar : (cnt - 1));
    const ushort* pA = act + (size_t)sr * INTER + scl;
    const size_t wrow = (size_t)e * HIDDEN + (size_t)(bn * DN_BN + r);
    const ushort* pB0 = wdb + wrow * INTER + scl;
    const ushort* pB1 = pB0 + (size_t)64 * INTER;

    const int fr = lane & 15;
    const int colsw = (((lane >> 4) ^ ((fr >> 1) & 3)) * 8);

    f32x4 acc[2][4] = {};

#define DN_STAGE(buf, t)                                              \
    do {                                                              \
        const int _o = (t) * BK;                                      \
        load_lds16(pA + _o,  &ldsA[buf][tid * 8]);                    \
        load_lds16(pB0 + _o, &ldsB[buf][tid * 8]);                    \
        load_lds16(pB1 + _o, &ldsB[buf][2048 + tid * 8]);             \
    } while (0)

#define DN_FRAGS_MFMA(cur)                                            \
    do {                                                              \
        const ushort* LA = ldsA[cur];                                 \
        const ushort* LB = ldsB[cur];                                 \
        short8 a[2], b[4];                                            \
        _Pragma("unroll")                                             \
        for (int m = 0; m < 2; m++)                                   \
            a[m] = *(const short8*)(LA + (wr * 32 + m * 16 + fr) * BK + colsw); \
        _Pragma("unroll")                                             \
        for (int n = 0; n < 4; n++)                                   \
            b[n] = *(const short8*)(LB + (wc * 64 + n * 16 + fr) * BK + colsw); \
        asm volatile("s_waitcnt lgkmcnt(0)" ::: "memory");            \
        asm volatile("s_barrier" ::: "memory");                       \
        if (t + 2 < NT) DN_STAGE(cur, t + 2);                         \
        _Pragma("unroll")                                             \
        for (int m = 0; m < 2; m++) {                                 \
            _Pragma("unroll")                                         \
            for (int n = 0; n < 4; n++)                               \
                acc[m][n] = __builtin_amdgcn_mfma_f32_16x16x32_bf16(a[m], b[n], acc[m][n], 0, 0, 0); \
        }                                                             \
    } while (0)

    const int NT = INTER / BK;   // 32
    DN_STAGE(0, 0);
    DN_STAGE(1, 1);

    for (int t = 0; t < NT - 1; ++t) {
        asm volatile("s_waitcnt vmcnt(3)" ::: "memory");
        asm volatile("s_barrier" ::: "memory");
        const int cur = t & 1;
        DN_FRAGS_MFMA(cur);
    }
    {
        const int t = NT - 1;
        asm volatile("s_waitcnt vmcnt(0)" ::: "memory");
        asm volatile("s_barrier" ::: "memory");
        const int cur = t & 1;
        DN_FRAGS_MFMA(cur);
    }
#undef DN_FRAGS_MFMA
#undef DN_STAGE

#pragma unroll
    for (int m = 0; m < 2; m++) {
#pragma unroll
        for (int rr = 0; rr < 4; rr++) {
            int row = bm * DN_BM + wr * 32 + m * 16 + (lane >> 4) * 4 + rr;
            if (row < cnt) {
                float* orow = out_e + (size_t)(b0 + row) * HIDDEN;
#pragma unroll
                for (int n = 0; n < 4; n++) {
                    int col = bn * DN_BN + wc * 64 + n * 16 + fr;
                    orow[col] = acc[m][n][rr];
                }
            }
        }
    }
}

// ---------------- gather: out[t] = w0*out_e[s0] + w1*out_e[s1] ----------------
__global__ __launch_bounds__(256) void moe_gather(const float* __restrict__ out_e,
                                                  const int* __restrict__ inv_slot,
                                                  const float* __restrict__ top_w,
                                                  float* __restrict__ out) {
    int t = blockIdx.x;
    int c = threadIdx.x * 8;
    int s0 = inv_slot[t * 2 + 0], s1 = inv_slot[t * 2 + 1];
    float w0 = top_w[t * 2 + 0], w1 = top_w[t * 2 + 1];
    const float4* r0 = (const float4*)(out_e + (size_t)s0 * HIDDEN + c);
    const float4* r1 = (const float4*)(out_e + (size_t)s1 * HIDDEN + c);
    float4* po = (float4*)(out + (size_t)t * HIDDEN + c);
#pragma unroll
    for (int j = 0; j < 2; j++) {
        float4 a = r0[j], b = r1[j], o;
        o.x = w0 * a.x + w1 * b.x;
        o.y = w0 * a.y + w1 * b.y;
        o.z = w0 * a.z + w1 * b.z;
        o.w = w0 * a.w + w1 * b.w;
        po[j] = o;
    }
}

// ---------------- launch ----------------
extern "C" void kernel_launch(void* const* d_in, const int* in_sizes, int n_in,
                              void* d_out, int out_size, void* d_ws, size_t ws_size,
                              hipStream_t stream) {
    const float* x  = (const float*)d_in[0];
    const float* gw = (const float*)d_in[1];
    const float* wg = (const float*)d_in[2];
    const float* wu = (const float*)d_in[3];
    const float* wd = (const float*)d_in[4];
    float* out = (float*)d_out;

    char* ws = (char*)d_ws;
    // [0,80MB): xb(16) + wgb(32) + wub(32) -- dead after gateup, ALIASED by out_e (67MB)
    ushort* xb  = (ushort*)(ws);
    ushort* wgb = (ushort*)(ws + (16u << 20));
    ushort* wub = (ushort*)(ws + (48u << 20));
    ushort* wdb = (ushort*)(ws + (80u << 20));
    ushort* act = (ushort*)(ws + (112u << 20));
    float* out_e = (float*)(ws);                       // alias, used after gateup
    char* p = ws + (128u << 20);
    int*   top_idx  = (int*)p;   p += 32768;
    float* top_w    = (float*)p; p += 32768;
    int*   slot_tok = (int*)p;   p += 32768;
    int*   inv_slot = (int*)p;   p += 32768;
    int*   counts   = (int*)p;   p += 128;
    int*   ebase    = (int*)p;   p += 128;
    int*   cursor   = (int*)p;   p += 128;

    hipMemsetAsync(counts, 0, 128, stream);

    cvt_bf16<<<1024, 256, 0, stream>>>(x,  xb,  (T_TOKENS * HIDDEN) / 8);
    cvt_bf16<<<1024, 256, 0, stream>>>(wg, wgb, (NUM_EXPERTS * INTER * HIDDEN) / 8);
    cvt_bf16<<<1024, 256, 0, stream>>>(wu, wub, (NUM_EXPERTS * INTER * HIDDEN) / 8);
    cvt_bf16<<<1024, 256, 0, stream>>>(wd, wdb, (NUM_EXPERTS * HIDDEN * INTER) / 8);

    moe_router<<<T_TOKENS / 4, 256, 0, stream>>>(x, gw, top_idx, top_w, counts);
    moe_offsets<<<1, 64, 0, stream>>>(counts, ebase, cursor);
    moe_scatter<<<(T_TOKENS + 255) / 256, 256, 0, stream>>>(top_idx, cursor, slot_tok, inv_slot);

    moe_gateup<<<4096, 256, 0, stream>>>(xb, wgb, wub, slot_tok, ebase, counts, act);
    moe_down<<<8192, 256, 0, stream>>>(act, wdb, ebase, counts, out_e);
    moe_gather<<<T_TOKENS, 256, 0, stream>>>(out_e, inv_slot, top_w, out);
}

// Round 8
// 596.279 us; speedup vs baseline: 1.0354x; 1.0075x over previous
//
#include <hip/hip_runtime.h>
#include <hip/hip_bf16.h>

#define NUM_EXPERTS 8
#define HIDDEN 2048
#define INTER 1024
#define T_TOKENS 4096

#define BK 32
#define GU_BM 128
#define GU_BN 128
#define DN_BM 128
#define DN_BN 256

typedef __attribute__((ext_vector_type(8))) short short8;
typedef __attribute__((ext_vector_type(8))) unsigned short ushort8_t;
typedef __attribute__((ext_vector_type(4))) float f32x4;

__device__ __forceinline__ ushort f2bf(float f) {
    __hip_bfloat16 h = __float2bfloat16(f);
    return *reinterpret_cast<ushort*>(&h);
}

__device__ __forceinline__ void load_lds16(const void* g, void* lds) {
    __builtin_amdgcn_global_load_lds(
        (const __attribute__((address_space(1))) void*)g,
        (__attribute__((address_space(3))) void*)lds, 16, 0, 0);
}

// ---------------- fused fp32 -> bf16 conversion, all 4 tensors ----------------
__global__ __launch_bounds__(256) void cvt_all(const float* __restrict__ x,  ushort* __restrict__ xb,
                                               const float* __restrict__ wg, ushort* __restrict__ wgb,
                                               const float* __restrict__ wu, ushort* __restrict__ wub,
                                               const float* __restrict__ wd, ushort* __restrict__ wdb) {
    const float* in; ushort* out; int n8;
    switch (blockIdx.y) {
        case 0:  in = x;  out = xb;  n8 = (T_TOKENS * HIDDEN) / 8; break;
        case 1:  in = wg; out = wgb; n8 = (NUM_EXPERTS * INTER * HIDDEN) / 8; break;
        case 2:  in = wu; out = wub; n8 = (NUM_EXPERTS * INTER * HIDDEN) / 8; break;
        default: in = wd; out = wdb; n8 = (NUM_EXPERTS * HIDDEN * INTER) / 8; break;
    }
    int i = blockIdx.x * 256 + threadIdx.x;
    int stride = gridDim.x * 256;
    for (; i < n8; i += stride) {
        const float4* p = (const float4*)in + 2 * (size_t)i;
        float4 a = p[0], b = p[1];
        ushort8_t o;
        o[0] = f2bf(a.x); o[1] = f2bf(a.y); o[2] = f2bf(a.z); o[3] = f2bf(a.w);
        o[4] = f2bf(b.x); o[5] = f2bf(b.y); o[6] = f2bf(b.z); o[7] = f2bf(b.w);
        *((ushort8_t*)out + i) = o;
    }
}

// ---------------- router: 4 waves/block, 1 token/wave ----------------
__global__ __launch_bounds__(256) void moe_router(const float* __restrict__ x,
                                                  const float* __restrict__ gw,
                                                  int* __restrict__ top_idx,
                                                  float* __restrict__ top_w,
                                                  int* __restrict__ counts) {
    int wid = threadIdx.x >> 6;
    int lane = threadIdx.x & 63;
    int t = blockIdx.x * 4 + wid;
    if (t >= T_TOKENS) return;
    const float* xt = x + (size_t)t * HIDDEN;
    float acc[NUM_EXPERTS];
#pragma unroll
    for (int e = 0; e < NUM_EXPERTS; e++) acc[e] = 0.f;
    for (int h = lane; h < HIDDEN; h += 64) {
        float xv = xt[h];
#pragma unroll
        for (int e = 0; e < NUM_EXPERTS; e++)
            acc[e] = fmaf(xv, gw[e * HIDDEN + h], acc[e]);
    }
#pragma unroll
    for (int e = 0; e < NUM_EXPERTS; e++) {
#pragma unroll
        for (int off = 32; off > 0; off >>= 1)
            acc[e] += __shfl_xor(acc[e], off);
    }
    if (lane == 0) {
        int i1 = 0; float l1 = acc[0];
#pragma unroll
        for (int e = 1; e < NUM_EXPERTS; e++)
            if (acc[e] > l1) { l1 = acc[e]; i1 = e; }
        int i2 = -1; float l2 = -3.4e38f;
#pragma unroll
        for (int e = 0; e < NUM_EXPERTS; e++)
            if (e != i1 && acc[e] > l2) { l2 = acc[e]; i2 = e; }
        float w2 = __expf(l2 - l1);
        float denom = 1.f + w2;
        top_idx[t * 2 + 0] = i1;
        top_idx[t * 2 + 1] = i2;
        top_w[t * 2 + 0] = 1.f / denom;
        top_w[t * 2 + 1] = w2 / denom;
        atomicAdd(&counts[i1], 1);
        atomicAdd(&counts[i2], 1);
    }
}

// ---------------- offsets ----------------
__global__ void moe_offsets(const int* __restrict__ counts,
                            int* __restrict__ ebase, int* __restrict__ cursor) {
    if (threadIdx.x == 0 && blockIdx.x == 0) {
        int s = 0;
        for (int e = 0; e < NUM_EXPERTS; e++) {
            ebase[e] = s; cursor[e] = s; s += counts[e];
        }
    }
}

// ---------------- scatter ----------------
__global__ __launch_bounds__(256) void moe_scatter(const int* __restrict__ top_idx,
                                                   int* __restrict__ cursor,
                                                   int* __restrict__ slot_tok,
                                                   int* __restrict__ inv_slot) {
    int t = blockIdx.x * 256 + threadIdx.x;
    if (t >= T_TOKENS) return;
#pragma unroll
    for (int k = 0; k < 2; k++) {
        int e = top_idx[t * 2 + k];
        int pos = atomicAdd(&cursor[e], 1);
        slot_tok[pos] = t;
        inv_slot[t * 2 + k] = pos;
    }
}

// ---------------- fused gate/up GEMM + SwiGLU, 128x128 ----------------
__global__ __launch_bounds__(256, 2) void moe_gateup(const ushort* __restrict__ xb,
                                                     const ushort* __restrict__ wgb,
                                                     const ushort* __restrict__ wub,
                                                     const int* __restrict__ slot_tok,
                                                     const int* __restrict__ ebase,
                                                     const int* __restrict__ ecnt,
                                                     ushort* __restrict__ act) {
    __shared__ ushort ldsA[2][GU_BM * BK];   // 2 x 8 KB
    __shared__ ushort ldsG[2][GU_BN * BK];   // 2 x 8 KB
    __shared__ ushort ldsU[2][GU_BN * BK];   // 2 x 8 KB

    // grid 2048: xcd = wg&7 owns 256 blocks = one expert; bm-major within.
    const int wg = blockIdx.x;
    const int wgid = (wg & 7) * 256 + (wg >> 3);
    const int e = wgid >> 8;
    const int rem = wgid & 255;
    const int bm = rem & 31;         // up to 32 tiles of 128 rows
    const int bn = rem >> 5;         // 0..7

    const int cnt = ecnt[e];
    if (bm * GU_BM >= cnt) return;
    const int b0 = ebase[e];

    const int tid = threadIdx.x;
    const int lane = tid & 63;
    const int wid = tid >> 6;
    const int wr = wid >> 1, wc = wid & 1;   // 2x2 waves, wave tile 64x64

    // staging: rows r and r+64, col chunk cs (swizzled source, linear LDS)
    const int r = tid >> 2, cs = tid & 3;
    const int scl = (cs ^ ((r >> 1) & 3)) * 8;   // swizzle invariant under r+64
    const int ar0 = bm * GU_BM + r;
    const int ar1 = ar0 + 64;
    const int tok0 = slot_tok[b0 + ((ar0 < cnt) ? ar0 : (cnt - 1))];
    const int tok1 = slot_tok[b0 + ((ar1 < cnt) ? ar1 : (cnt - 1))];
    const ushort* pA0 = xb + (size_t)tok0 * HIDDEN + scl;
    const ushort* pA1 = xb + (size_t)tok1 * HIDDEN + scl;
    const size_t wrow0 = (size_t)e * INTER + (size_t)(bn * GU_BN + r);
    const ushort* pG0 = wgb + wrow0 * HIDDEN + scl;
    const ushort* pG1 = pG0 + (size_t)64 * HIDDEN;
    const ushort* pU0 = wub + wrow0 * HIDDEN + scl;
    const ushort* pU1 = pU0 + (size_t)64 * HIDDEN;

    const int fr = lane & 15;
    const int colsw = (((lane >> 4) ^ ((fr >> 1) & 3)) * 8);

    f32x4 accg[4][4] = {};
    f32x4 accu[4][4] = {};

#define GU_STAGE(buf, t)                                              \
    do {                                                              \
        const int _o = (t) * BK;                                      \
        load_lds16(pA0 + _o, &ldsA[buf][tid * 8]);                    \
        load_lds16(pA1 + _o, &ldsA[buf][2048 + tid * 8]);             \
        load_lds16(pG0 + _o, &ldsG[buf][tid * 8]);                    \
        load_lds16(pG1 + _o, &ldsG[buf][2048 + tid * 8]);             \
        load_lds16(pU0 + _o, &ldsU[buf][tid * 8]);                    \
        load_lds16(pU1 + _o, &ldsU[buf][2048 + tid * 8]);             \
    } while (0)

#define GU_FRAGS_MFMA(cur)                                            \
    do {                                                              \
        const ushort* LA = ldsA[cur];                                 \
        const ushort* LG = ldsG[cur];                                 \
        const ushort* LU = ldsU[cur];                                 \
        short8 a[4], bg[4], bu[4];                                    \
        _Pragma("unroll")                                             \
        for (int m = 0; m < 4; m++)                                   \
            a[m] = *(const short8*)(LA + (wr * 64 + m * 16 + fr) * BK + colsw); \
        _Pragma("unroll")                                             \
        for (int n = 0; n < 4; n++) {                                 \
            bg[n] = *(const short8*)(LG + (wc * 64 + n * 16 + fr) * BK + colsw); \
            bu[n] = *(const short8*)(LU + (wc * 64 + n * 16 + fr) * BK + colsw); \
        }                                                             \
        asm volatile("s_waitcnt lgkmcnt(0)" ::: "memory");            \
        asm volatile("s_barrier" ::: "memory");                       \
        if (t + 2 < NT) GU_STAGE(cur, t + 2);                         \
        _Pragma("unroll")                                             \
        for (int m = 0; m < 4; m++) {                                 \
            _Pragma("unroll")                                         \
            for (int n = 0; n < 4; n++) {                             \
                accg[m][n] = __builtin_amdgcn_mfma_f32_16x16x32_bf16(a[m], bg[n], accg[m][n], 0, 0, 0); \
                accu[m][n] = __builtin_amdgcn_mfma_f32_16x16x32_bf16(a[m], bu[n], accu[m][n], 0, 0, 0); \
            }                                                         \
        }                                                             \
    } while (0)

    const int NT = HIDDEN / BK;   // 64
    GU_STAGE(0, 0);
    GU_STAGE(1, 1);

    for (int t = 0; t < NT - 1; ++t) {
        asm volatile("s_waitcnt vmcnt(6)" ::: "memory");   // stage t done, t+1 in flight
        asm volatile("s_barrier" ::: "memory");
        const int cur = t & 1;
        GU_FRAGS_MFMA(cur);
    }
    {
        const int t = NT - 1;
        asm volatile("s_waitcnt vmcnt(0)" ::: "memory");
        asm volatile("s_barrier" ::: "memory");
        const int cur = t & 1;
        GU_FRAGS_MFMA(cur);
    }
#undef GU_FRAGS_MFMA
#undef GU_STAGE

#pragma unroll
    for (int m = 0; m < 4; m++) {
#pragma unroll
        for (int rr = 0; rr < 4; rr++) {
            int row = bm * GU_BM + wr * 64 + m * 16 + (lane >> 4) * 4 + rr;
            if (row < cnt) {
                size_t arow = (size_t)(b0 + row) * INTER;
#pragma unroll
                for (int n = 0; n < 4; n++) {
                    int col = bn * GU_BN + wc * 64 + n * 16 + fr;
                    float g = accg[m][n][rr];
                    float u = accu[m][n][rr];
                    float s = g / (1.f + __expf(-g));
                    act[arow + col] = f2bf(s * u);
                }
            }
        }
    }
}

// ---------------- down GEMM 128x256: plain fp32 stores to out_e ----------------
__global__ __launch_bounds__(256, 2) void moe_down(const ushort* __restrict__ act,
                                                   const ushort* __restrict__ wdb,
                                                   const int* __restrict__ ebase,
                                                   const int* __restrict__ ecnt,
                                                   float* __restrict__ out_e) {
    __shared__ ushort ldsA[2][DN_BM * BK];   // 2 x 8 KB
    __shared__ ushort ldsB[2][DN_BN * BK];   // 2 x 16 KB

    const int wg = blockIdx.x;
    const int wgid = (wg & 7) * 256 + (wg >> 3);
    const int e = wgid >> 8;
    const int rem = wgid & 255;
    const int bm = rem & 31;         // up to 32 tiles of 128 rows
    const int bn = rem >> 5;         // 0..7 tiles of 256 cols

    const int cnt = ecnt[e];
    if (bm * DN_BM >= cnt) return;
    const int b0 = ebase[e];

    const int tid = threadIdx.x;
    const int lane = tid & 63;
    const int wid = tid >> 6;
    const int wr = wid >> 1, wc = wid & 1;   // wave tile 64 rows x 128 cols

    const int r = tid >> 2, cs = tid & 3;
    const int scl = (cs ^ ((r >> 1) & 3)) * 8;
    const int ar0 = bm * DN_BM + r;
    const int ar1 = ar0 + 64;
    const int sr0 = b0 + ((ar0 < cnt) ? ar0 : (cnt - 1));
    const int sr1 = b0 + ((ar1 < cnt) ? ar1 : (cnt - 1));
    const ushort* pA0 = act + (size_t)sr0 * INTER + scl;
    const ushort* pA1 = act + (size_t)sr1 * INTER + scl;
    const size_t wrow = (size_t)e * HIDDEN + (size_t)(bn * DN_BN + r);
    const ushort* pB0 = wdb + wrow * INTER + scl;
    const ushort* pB1 = pB0 + (size_t)64 * INTER;
    const ushort* pB2 = pB0 + (size_t)128 * INTER;
    const ushort* pB3 = pB0 + (size_t)192 * INTER;

    const int fr = lane & 15;
    const int colsw = (((lane >> 4) ^ ((fr >> 1) & 3)) * 8);

    f32x4 acc[4][8] = {};

#define DN_STAGE(buf, t)                                              \
    do {                                                              \
        const int _o = (t) * BK;                                      \
        load_lds16(pA0 + _o, &ldsA[buf][tid * 8]);                    \
        load_lds16(pA1 + _o, &ldsA[buf][2048 + tid * 8]);             \
        load_lds16(pB0 + _o, &ldsB[buf][tid * 8]);                    \
        load_lds16(pB1 + _o, &ldsB[buf][2048 + tid * 8]);             \
        load_lds16(pB2 + _o, &ldsB[buf][4096 + tid * 8]);             \
        load_lds16(pB3 + _o, &ldsB[buf][6144 + tid * 8]);             \
    } while (0)

#define DN_FRAGS_MFMA(cur)                                            \
    do {                                                              \
        const ushort* LA = ldsA[cur];                                 \
        const ushort* LB = ldsB[cur];                                 \
        short8 a[4], b[8];                                            \
        _Pragma("unroll")                                             \
        for (int m = 0; m < 4; m++)                                   \
            a[m] = *(const short8*)(LA + (wr * 64 + m * 16 + fr) * BK + colsw); \
        _Pragma("unroll")                                             \
        for (int n = 0; n < 8; n++)                                   \
            b[n] = *(const short8*)(LB + (wc * 128 + n * 16 + fr) * BK + colsw); \
        asm volatile("s_waitcnt lgkmcnt(0)" ::: "memory");            \
        asm volatile("s_barrier" ::: "memory");                       \
        if (t + 2 < NT) DN_STAGE(cur, t + 2);                         \
        _Pragma("unroll")                                             \
        for (int m = 0; m < 4; m++) {                                 \
            _Pragma("unroll")                                         \
            for (int n = 0; n < 8; n++)                               \
                acc[m][n] = __builtin_amdgcn_mfma_f32_16x16x32_bf16(a[m], b[n], acc[m][n], 0, 0, 0); \
        }                                                             \
    } while (0)

    const int NT = INTER / BK;   // 32
    DN_STAGE(0, 0);
    DN_STAGE(1, 1);

    for (int t = 0; t < NT - 1; ++t) {
        asm volatile("s_waitcnt vmcnt(6)" ::: "memory");
        asm volatile("s_barrier" ::: "memory");
        const int cur = t & 1;
        DN_FRAGS_MFMA(cur);
    }
    {
        const int t = NT - 1;
        asm volatile("s_waitcnt vmcnt(0)" ::: "memory");
        asm volatile("s_barrier" ::: "memory");
        const int cur = t & 1;
        DN_FRAGS_MFMA(cur);
    }
#undef DN_FRAGS_MFMA
#undef DN_STAGE

#pragma unroll
    for (int m = 0; m < 4; m++) {
#pragma unroll
        for (int rr = 0; rr < 4; rr++) {
            int row = bm * DN_BM + wr * 64 + m * 16 + (lane >> 4) * 4 + rr;
            if (row < cnt) {
                float* orow = out_e + (size_t)(b0 + row) * HIDDEN;
#pragma unroll
                for (int n = 0; n < 8; n++) {
                    int col = bn * DN_BN + wc * 128 + n * 16 + fr;
                    orow[col] = acc[m][n][rr];
                }
            }
        }
    }
}

// ---------------- gather: out[t] = w0*out_e[s0] + w1*out_e[s1] ----------------
__global__ __launch_bounds__(256) void moe_gather(const float* __restrict__ out_e,
                                                  const int* __restrict__ inv_slot,
                                                  const float* __restrict__ top_w,
                                                  float* __restrict__ out) {
    int t = blockIdx.x;
    int c = threadIdx.x * 8;
    int s0 = inv_slot[t * 2 + 0], s1 = inv_slot[t * 2 + 1];
    float w0 = top_w[t * 2 + 0], w1 = top_w[t * 2 + 1];
    const float4* r0 = (const float4*)(out_e + (size_t)s0 * HIDDEN + c);
    const float4* r1 = (const float4*)(out_e + (size_t)s1 * HIDDEN + c);
    float4* po = (float4*)(out + (size_t)t * HIDDEN + c);
#pragma unroll
    for (int j = 0; j < 2; j++) {
        float4 a = r0[j], b = r1[j], o;
        o.x = w0 * a.x + w1 * b.x;
        o.y = w0 * a.y + w1 * b.y;
        o.z = w0 * a.z + w1 * b.z;
        o.w = w0 * a.w + w1 * b.w;
        po[j] = o;
    }
}

// ---------------- launch ----------------
extern "C" void kernel_launch(void* const* d_in, const int* in_sizes, int n_in,
                              void* d_out, int out_size, void* d_ws, size_t ws_size,
                              hipStream_t stream) {
    const float* x  = (const float*)d_in[0];
    const float* gw = (const float*)d_in[1];
    const float* wg = (const float*)d_in[2];
    const float* wu = (const float*)d_in[3];
    const float* wd = (const float*)d_in[4];
    float* out = (float*)d_out;

    char* ws = (char*)d_ws;
    // [0,80MB): xb(16) + wgb(32) + wub(32) -- dead after gateup, ALIASED by out_e (67MB)
    ushort* xb  = (ushort*)(ws);
    ushort* wgb = (ushort*)(ws + (16u << 20));
    ushort* wub = (ushort*)(ws + (48u << 20));
    ushort* wdb = (ushort*)(ws + (80u << 20));
    ushort* act = (ushort*)(ws + (112u << 20));
    float* out_e = (float*)(ws);                       // alias, used after gateup
    char* p = ws + (128u << 20);
    int*   top_idx  = (int*)p;   p += 32768;
    float* top_w    = (float*)p; p += 32768;
    int*   slot_tok = (int*)p;   p += 32768;
    int*   inv_slot = (int*)p;   p += 32768;
    int*   counts   = (int*)p;   p += 128;
    int*   ebase    = (int*)p;   p += 128;
    int*   cursor   = (int*)p;   p += 128;

    hipMemsetAsync(counts, 0, 128, stream);

    cvt_all<<<dim3(768, 4), 256, 0, stream>>>(x, xb, wg, wgb, wu, wub, wd, wdb);

    moe_router<<<T_TOKENS / 4, 256, 0, stream>>>(x, gw, top_idx, top_w, counts);
    moe_offsets<<<1, 64, 0, stream>>>(counts, ebase, cursor);
    moe_scatter<<<(T_TOKENS + 255) / 256, 256, 0, stream>>>(top_idx, cursor, slot_tok, inv_slot);

    moe_gateup<<<2048, 256, 0, stream>>>(xb, wgb, wub, slot_tok, ebase, counts, act);
    moe_down<<<2048, 256, 0, stream>>>(act, wdb, ebase, counts, out_e);
    moe_gather<<<T_TOKENS, 256, 0, stream>>>(out_e, inv_slot, top_w, out);
}